// Round 4
// baseline (2071.543 us; speedup 1.0000x reference)
//
#include <hip/hip_runtime.h>

typedef _Float16 f16;
typedef _Float16 f16x8 __attribute__((ext_vector_type(8)));
typedef float f32x16 __attribute__((ext_vector_type(16)));

// async global->LDS, 16B per lane; LDS dest must be linear (base + lane*16).
__device__ __forceinline__ void gload_lds16(const void* g, void* l) {
  __builtin_amdgcn_global_load_lds(
      (const __attribute__((address_space(1))) void*)g,
      (__attribute__((address_space(3))) void*)l, 16, 0, 0);
}

__device__ __forceinline__ float act_apply(float x, int id) {
  switch (id) {
    case 0: return fmaxf(x, 0.0f);
    case 1: return 1.0f / (1.0f + __expf(-x));
    case 2: return tanhf(x);
    case 3: return x >= 0.0f ? x : 0.1f * x;
    default: return 1.0507009873554805f *
                    (x > 0.0f ? x : 1.6732632423543772f * expm1f(x));
  }
}

// C = act(A @ W^T * Sa + bias) * invSn
// 256x256 tile, BK=32, 4-slot LDS ring, m201-style 2-phase-per-iter schedule,
// 32x32x16 f16 MFMA, counted vmcnt (8/4/0), swizzled LDS.
template <bool FINAL>
__global__ __launch_bounds__(512, 2)
void gemm_bias_act(const f16* __restrict__ A, const f16* __restrict__ W,
                   const float* __restrict__ bias, const int* __restrict__ ids,
                   float Sa, float invSn, void* __restrict__ outv,
                   int M, int N, int K) {
  __shared__ f16 lA[4][256 * 32];   // 4 x 16 KiB
  __shared__ f16 lB[4][256 * 32];   // 4 x 16 KiB  (total 128 KiB)

  const int tid  = (int)threadIdx.x;
  const int lane = tid & 63;
  const int wid  = tid >> 6;   // 0..7
  const int wm   = wid >> 2;   // 0..1 : row half (128 rows)
  const int wn   = wid & 3;    // 0..3 : col quarter (64 cols)

  // bijective XCD-aware swizzle (nwg % 8 == 0 for all shapes here)
  const int nbx = N >> 8;
  const int nwg = (M >> 8) * nbx;
  const int b   = (int)blockIdx.x;
  const int swz = (b & 7) * (nwg >> 3) + (b >> 3);
  const int brow = (swz / nbx) << 8;
  const int bcol = (swz % nbx) << 8;

  // ---- staging: pre-swizzled global source, linear LDS dest (validated r2/r3) ----
  const int d0 = tid << 4;            // dest byte 0..8191
  const int d1 = d0 + 8192;           // dest byte 8192..16383
  const int s0 = d0 ^ (((d0 >> 7) & 7) << 4);
  const int s1 = d1 ^ (((d1 >> 7) & 7) << 4);
  const int r0 = s0 >> 6, c0 = (s0 >> 4) & 3;   // source row, 16B-block in K
  const int r1 = s1 >> 6, c1 = (s1 >> 4) & 3;

  const f16* pA0 = A + (long)(brow + r0) * K + c0 * 8;
  const f16* pA1 = A + (long)(brow + r1) * K + c1 * 8;
  const f16* pB0 = W + (long)(bcol + r0) * K + c0 * 8;
  const f16* pB1 = W + (long)(bcol + r1) * K + c1 * 8;
  const int e0 = tid << 3;            // LDS dest in elements
  const int e1 = e0 + 4096;

  // ---- fragment read addressing (swizzled), 32x32x16 operand layout ----
  // A/B input: row(col) = lane&31, k = 8*(lane>>5) within each K16 half.
  const int l31 = lane & 31;
  const int lhi = lane >> 5;
  const int xorv = ((l31 >> 1) & 7) << 4;   // matches staging involution
  const char* baA = (const char*)&lA[0][0];
  const char* baB = (const char*)&lB[0][0];

  int offA[4][2], offB[2][2];
#pragma unroll
  for (int m = 0; m < 4; ++m)
#pragma unroll
    for (int kh = 0; kh < 2; ++kh)
      offA[m][kh] = (((wm * 128 + m * 32 + l31) << 6) + ((2 * kh + lhi) << 4)) ^ xorv;
#pragma unroll
  for (int n = 0; n < 2; ++n)
#pragma unroll
    for (int kh = 0; kh < 2; ++kh)
      offB[n][kh] = (((wn * 64 + n * 32 + l31) << 6) + ((2 * kh + lhi) << 4)) ^ xorv;

  f32x16 acc[4][2];
#pragma unroll
  for (int m = 0; m < 4; ++m)
#pragma unroll
    for (int n = 0; n < 2; ++n)
#pragma unroll
      for (int r = 0; r < 16; ++r) acc[m][n][r] = 0.0f;

  const int nt = K >> 5;   // 64 or 128

  // prologue: 3 tiles fully staged (12 loads, per-thread issue order monotone)
#pragma unroll
  for (int t = 0; t < 3; ++t) {
    const long kk = (long)t << 5;
    gload_lds16(pA0 + kk, &lA[t][e0]);
    gload_lds16(pA1 + kk, &lA[t][e1]);
    gload_lds16(pB0 + kk, &lB[t][e0]);
    gload_lds16(pB1 + kk, &lB[t][e1]);
  }
  asm volatile("s_waitcnt vmcnt(8)" ::: "memory");  // tile 0 landed (this wave)
  __builtin_amdgcn_s_barrier();                     // ... and all waves
  asm volatile("" ::: "memory");

  for (int i = 0; i < nt; ++i) {
    const int so  = (i & 3) << 14;          // current slot byte offset
    const int ps  = (i + 3) & 3;            // prefetch slot (= (i-1)&3)
    const long kk3 = (long)(i + 3) << 5;
    const bool pf = (i + 3) < nt;

    f16x8 af[4], bf[2];

    // ================= phase 0 : k-half 0 =================
#pragma unroll
    for (int m = 0; m < 4; ++m) af[m] = *(const f16x8*)(baA + so + offA[m][0]);
#pragma unroll
    for (int n = 0; n < 2; ++n) bf[n] = *(const f16x8*)(baB + so + offB[n][0]);
    if (pf) {
      gload_lds16(pA0 + kk3, &lA[ps][e0]);
      gload_lds16(pB0 + kk3, &lB[ps][e0]);
    }
    __builtin_amdgcn_s_barrier();
    asm volatile("s_waitcnt lgkmcnt(0)" ::: "memory");
    __builtin_amdgcn_sched_barrier(0);
    __builtin_amdgcn_s_setprio(1);
#pragma unroll
    for (int m = 0; m < 4; ++m)
#pragma unroll
      for (int n = 0; n < 2; ++n)
        acc[m][n] = __builtin_amdgcn_mfma_f32_32x32x16_f16(af[m], bf[n],
                                                           acc[m][n], 0, 0, 0);
    __builtin_amdgcn_s_setprio(0);
    __builtin_amdgcn_sched_barrier(0);
    __builtin_amdgcn_s_barrier();

    // ================= phase 1 : k-half 1 =================
#pragma unroll
    for (int m = 0; m < 4; ++m) af[m] = *(const f16x8*)(baA + so + offA[m][1]);
#pragma unroll
    for (int n = 0; n < 2; ++n) bf[n] = *(const f16x8*)(baB + so + offB[n][1]);
    if (pf) {
      gload_lds16(pA1 + kk3, &lA[ps][e1]);
      gload_lds16(pB1 + kk3, &lB[ps][e1]);
    }
    __builtin_amdgcn_s_barrier();
    asm volatile("s_waitcnt lgkmcnt(0)" ::: "memory");
    __builtin_amdgcn_sched_barrier(0);
    __builtin_amdgcn_s_setprio(1);
#pragma unroll
    for (int m = 0; m < 4; ++m)
#pragma unroll
      for (int n = 0; n < 2; ++n)
        acc[m][n] = __builtin_amdgcn_mfma_f32_32x32x16_f16(af[m], bf[n],
                                                           acc[m][n], 0, 0, 0);
    __builtin_amdgcn_s_setprio(0);
    __builtin_amdgcn_sched_barrier(0);

    // ---- iteration boundary: tile i+1 must be fully landed (all waves) ----
    if (i < nt - 1) {
      // outstanding allowed: tiles i+2, i+3 (4 loads each, as staged)
      if (i <= nt - 4)      asm volatile("s_waitcnt vmcnt(8)" ::: "memory");
      else if (i == nt - 3) asm volatile("s_waitcnt vmcnt(4)" ::: "memory");
      else                  asm volatile("s_waitcnt vmcnt(0)" ::: "memory");
      __builtin_amdgcn_s_barrier();
      asm volatile("" ::: "memory");
    }
  }

  // D layout (m74/m101-verified): col = lane&31, row = (r&3) + 8*(r>>2) + 4*(lane>>5)
#pragma unroll
  for (int n = 0; n < 2; ++n) {
    const int gcol = bcol + wn * 64 + n * 32 + l31;
    const float bv = bias[gcol];
    const int id   = ids[gcol];
#pragma unroll
    for (int m = 0; m < 4; ++m) {
      const int rbase = brow + wm * 128 + m * 32 + 4 * lhi;
#pragma unroll
      for (int r = 0; r < 16; ++r) {
        const int grow = rbase + (r & 3) + 8 * (r >> 2);
        const float y = act_apply(acc[m][n][r] * Sa + bv, id);
        if (FINAL) {
          ((float*)outv)[(long)grow * N + gcol] = y;
        } else {
          ((f16*)outv)[(long)grow * N + gcol] = (f16)(y * invSn);
        }
      }
    }
  }
}

__global__ void cvt_f32_to_f16(const float* __restrict__ in, f16* __restrict__ out,
                               float scale, int n) {
  int i = ((int)blockIdx.x * 256 + (int)threadIdx.x) * 8;
  const int stride = (int)gridDim.x * 256 * 8;
  for (; i < n; i += stride) {
    const float4 v0 = *(const float4*)(in + i);
    const float4 v1 = *(const float4*)(in + i + 4);
    f16x8 h;
    h[0] = (f16)(v0.x * scale); h[1] = (f16)(v0.y * scale);
    h[2] = (f16)(v0.z * scale); h[3] = (f16)(v0.w * scale);
    h[4] = (f16)(v1.x * scale); h[5] = (f16)(v1.y * scale);
    h[6] = (f16)(v1.z * scale); h[7] = (f16)(v1.w * scale);
    *(f16x8*)(out + i) = h;
  }
}

extern "C" void kernel_launch(void* const* d_in, const int* in_sizes, int n_in,
                              void* d_out, int out_size, void* d_ws, size_t ws_size,
                              hipStream_t stream) {
  (void)in_sizes; (void)n_in; (void)out_size; (void)ws_size;
  const int M = 8192, IND = 2048, HID = 4096, OUTD = 2048;
  const float* x = (const float*)d_in[0];

  // workspace: actA (8192*4096 f16) | actB (8192*4096 f16) | wbuf (4096*4096 f16)
  f16* actA = (f16*)d_ws;
  f16* actB = actA + (size_t)M * HID;
  f16* wbuf = actB + (size_t)M * HID;

  // static per-layer activation scales (powers of 2, exact): h_i stored as h/S[i]
  const float S[6] = {1.f, 16.f, 512.f, 16384.f, 262144.f, 8388608.f};

  const int Ks[6] = {IND, HID, HID, HID, HID, HID};
  const int Ns[6] = {HID, HID, HID, HID, HID, OUTD};

  cvt_f32_to_f16<<<2048, 256, 0, stream>>>(x, actA, 1.0f, M * IND);

  f16* cur = actA;
  f16* nxt = actB;
  for (int i = 0; i < 6; ++i) {
    const int K = Ks[i], N = Ns[i];
    const float* w  = (const float*)d_in[1 + 3 * i];
    const float* bs = (const float*)d_in[2 + 3 * i];
    const int* id   = (const int*)d_in[3 + 3 * i];

    cvt_f32_to_f16<<<2048, 256, 0, stream>>>(w, wbuf, 1.0f, N * K);

    const int nblk = (M >> 8) * (N >> 8);
    if (i < 5) {
      gemm_bias_act<false><<<nblk, 512, 0, stream>>>(
          cur, wbuf, bs, id, S[i], 1.0f / S[i + 1], nxt, M, N, K);
      f16* t = cur; cur = nxt; nxt = t;
    } else {
      gemm_bias_act<true><<<nblk, 512, 0, stream>>>(
          cur, wbuf, bs, id, S[i], 1.0f, d_out, M, N, K);
    }
  }
}